// Round 14
// baseline (357.300 us; speedup 1.0000x reference)
//
#include <hip/hip_runtime.h>
#include <hip/hip_bf16.h>

#define TOK   4096            // B*S
#define DDIM  1024
#define NEXP  8
#define HDIM  4096
#define KSEL  2
#define NPAIR (TOK * KSEL)    // 8192
#define NSPLIT 4              // gemm2 split-K factor
#define MAXT  40              // max populated (expert, 256-row M-tile) entries

typedef __attribute__((ext_vector_type(8))) _Float16 f16x8;
typedef __attribute__((ext_vector_type(4))) _Float16 f16x4;
typedef __attribute__((ext_vector_type(4))) float    f32x4;

__device__ __forceinline__ void gload16(const void* g, void* l) {
  __builtin_amdgcn_global_load_lds((const __attribute__((address_space(1))) void*)g,
                                   (__attribute__((address_space(3))) void*)l, 16, 0, 0);
}

__device__ __forceinline__ float gelu_tanh(float u) {
  float inner = 0.7978845608028654f * (u + 0.044715f * u * u * u);
  float t2 = __expf(2.f * inner);
  return u - u / (t2 + 1.f);     // == 0.5*u*(1+tanh(inner)), overflow-safe
}

// ---------------- router (+ fused x->fp16): one wave per token ----------------
__global__ __launch_bounds__(256) void k_router(const float* __restrict__ x,
    const float* __restrict__ rw, const float* __restrict__ rb,
    int* __restrict__ tidx, float* __restrict__ tw,
    _Float16* __restrict__ xb) {
  const int t    = blockIdx.x * 4 + (threadIdx.x >> 6);
  const int lane = threadIdx.x & 63;
  const float* xr = x + (size_t)t * DDIM;
  _Float16*   xbr = xb + (size_t)t * DDIM;
  float acc[NEXP];
#pragma unroll
  for (int e = 0; e < NEXP; ++e) acc[e] = 0.f;
  for (int d0 = lane * 4; d0 < DDIM; d0 += 256) {
    const float4 xv = *(const float4*)(xr + d0);
    f16x4 hx;
    hx[0] = (_Float16)xv.x; hx[1] = (_Float16)xv.y;
    hx[2] = (_Float16)xv.z; hx[3] = (_Float16)xv.w;
    *(f16x4*)(xbr + d0) = hx;
#pragma unroll
    for (int i = 0; i < 4; ++i) {
      const float xs = (&xv.x)[i];
      const float4 r0 = *(const float4*)(rw + (size_t)(d0 + i) * NEXP);
      const float4 r1 = *(const float4*)(rw + (size_t)(d0 + i) * NEXP + 4);
      acc[0] += xs * r0.x; acc[1] += xs * r0.y; acc[2] += xs * r0.z; acc[3] += xs * r0.w;
      acc[4] += xs * r1.x; acc[5] += xs * r1.y; acc[6] += xs * r1.z; acc[7] += xs * r1.w;
    }
  }
#pragma unroll
  for (int e = 0; e < NEXP; ++e) {
    float v = acc[e];
#pragma unroll
    for (int s = 32; s; s >>= 1) v += __shfl_xor(v, s, 64);
    acc[e] = v;
  }
  if (lane == 0) {
    float lg[NEXP];
#pragma unroll
    for (int e = 0; e < NEXP; ++e) lg[e] = acc[e] + rb[e];
    int i0 = 0;
#pragma unroll
    for (int e = 1; e < NEXP; ++e) if (lg[e] > lg[i0]) i0 = e;
    int i1 = -1; float best = -3.4e38f;
#pragma unroll
    for (int e = 0; e < NEXP; ++e) {
      if (e == i0) continue;
      if (lg[e] > best) { best = lg[e]; i1 = e; }
    }
    float w0 = 1.f / (1.f + expf(lg[i1] - lg[i0]));
    tidx[t * 2]     = i0;  tidx[t * 2 + 1] = i1;
    tw[t * 2]       = w0;  tw[t * 2 + 1]   = 1.f - w0;
  }
}

// ---------------- scan: histogram + prefix + scatter + compact 256-row tile list ----------------
__global__ __launch_bounds__(1024) void k_scan(const int* __restrict__ tidx,
                       const float* __restrict__ tw,
                       int* __restrict__ offs,
                       int* __restrict__ row_token, float* __restrict__ row_w,
                       int* __restrict__ inv,
                       int* __restrict__ tlist, int* __restrict__ tcount) {
  __shared__ int hist[NEXP];
  __shared__ int soff[NEXP + 1];
  __shared__ int scur[NEXP];
  if (threadIdx.x < NEXP) hist[threadIdx.x] = 0;
  __syncthreads();
  const int lane = threadIdx.x & 63;
  int e_loc[NPAIR / 1024];
#pragma unroll
  for (int it = 0; it < NPAIR / 1024; ++it) {
    const int p = it * 1024 + threadIdx.x;
    const int e = tidx[p];
    e_loc[it] = e;
#pragma unroll
    for (int ee = 0; ee < NEXP; ++ee) {
      unsigned long long m = __ballot(e == ee);
      if (m && lane == 0) atomicAdd(&hist[ee], __popcll(m));
    }
  }
  __syncthreads();
  if (threadIdx.x == 0) {
    int run = 0;
    for (int e = 0; e < NEXP; ++e) { soff[e] = run; scur[e] = run; run += hist[e]; }
    soff[NEXP] = run;
    for (int e = 0; e <= NEXP; ++e) offs[e] = soff[e];
    // compact (expert, 256-row m-tile) work list: all entries populated, tail contiguous
    int cnt = 0;
    for (int e = 0; e < NEXP; ++e) {
      const int ne = soff[e + 1] - soff[e];
      for (int m = 0; m < ne; m += 256) tlist[cnt++] = (e << 8) | (m >> 8);
    }
    *tcount = cnt;
  }
  __syncthreads();
#pragma unroll
  for (int it = 0; it < NPAIR / 1024; ++it) {
    const int p = it * 1024 + threadIdx.x;
    const int e = e_loc[it];
    int pos = 0;
#pragma unroll
    for (int ee = 0; ee < NEXP; ++ee) {
      unsigned long long m = __ballot(e == ee);
      if (!m) continue;
      int base = 0;
      if (lane == 0) base = atomicAdd(&scur[ee], __popcll(m));
      base = __shfl(base, 0, 64);
      if (e == ee) pos = base + __popcll(m & ((1ull << lane) - 1ull));
    }
    row_token[pos] = p >> 1;
    row_w[pos]     = tw[p];
    inv[p]         = pos;
  }
}

// ---------------- both weight transposes, one dispatch ----------------
__global__ __launch_bounds__(256) void k_transpose2(const float* __restrict__ w1,
    const float* __restrict__ w2, _Float16* __restrict__ w1t, _Float16* __restrict__ w2t) {
  __shared__ _Float16 tile[64][72];
  const int zz = blockIdx.y;
  const float* ip; _Float16* op; int Rr, Cc, i0, j0;
  if (zz < NEXP) {
    ip = w1 + (size_t)zz * DDIM * HDIM;  op = w1t + (size_t)zz * DDIM * HDIM;
    Rr = DDIM; Cc = HDIM;
    i0 = (blockIdx.x >> 6) * 64; j0 = (blockIdx.x & 63) * 64;
  } else {
    ip = w2 + (size_t)(zz - NEXP) * HDIM * DDIM;  op = w2t + (size_t)(zz - NEXP) * HDIM * DDIM;
    Rr = HDIM; Cc = DDIM;
    i0 = (blockIdx.x >> 4) * 64; j0 = (blockIdx.x & 15) * 64;
  }
  const int tx = threadIdx.x & 15, ty = threadIdx.x >> 4;
#pragma unroll
  for (int rr = 0; rr < 4; ++rr) {
    int r = ty + rr * 16;
    float4 v = *(const float4*)(ip + (size_t)(i0 + r) * Cc + j0 + tx * 4);
    tile[r][tx * 4 + 0] = (_Float16)v.x;
    tile[r][tx * 4 + 1] = (_Float16)v.y;
    tile[r][tx * 4 + 2] = (_Float16)v.z;
    tile[r][tx * 4 + 3] = (_Float16)v.w;
  }
  __syncthreads();
#pragma unroll
  for (int cc = 0; cc < 4; ++cc) {
    int c = ty + cc * 16;
    f16x4 o;
#pragma unroll
    for (int k = 0; k < 4; ++k) o[k] = tile[tx * 4 + k][c];
    *(f16x4*)(op + (size_t)(j0 + c) * Rr + i0 + tx * 4) = o;
  }
}

// =======================================================================
// 256x256 8-phase GEMM (r12 body, verified refcheck) on a COMPACT 1D tile
// list (r13): active blocks are a contiguous prefix -> even CU spread at the
// 1-block/CU residency this 128KB-LDS kernel runs at.
// =======================================================================
template <bool G1>
__global__ __launch_bounds__(512, 2) void k_gemm256(
    const _Float16* __restrict__ A,     // G1: xb [TOK][DDIM]; G2: hbuf [NPAIR][HDIM]
    const _Float16* __restrict__ Bw,    // G1: w1t [E][HDIM][DDIM]; G2: w2t [E][DDIM][HDIM]
    const float* __restrict__ bias_g,   // G1: b1; G2 unused
    const int* __restrict__ offs,
    const int* __restrict__ row_token,  // G1 gather
    const int* __restrict__ tlist, const int* __restrict__ tcount,
    _Float16* __restrict__ outb) {      // G1: hbuf; G2: yb (NSPLIT partials)
  const int bid = blockIdx.x;
  const int t   = bid >> 4;
  if (t >= *tcount) return;
  const int tl  = tlist[t];
  const int e   = tl >> 8;
  const int m0  = (tl & 255) << 8;      // *256
  int nx, kh;
  if (G1) { nx = bid & 15; kh = 0; }
  else    { const int sub = bid & 15; kh = sub >> 2; nx = sub & 3; }
  const int n0  = nx * 256;
  const int off0 = offs[e];
  const int ne   = offs[e + 1] - off0;
  const int mrem = ne - m0;

  constexpr int RSTR = G1 ? (DDIM * 2) : (HDIM * 2);   // row bytes for A and B
  constexpr int OSTR = G1 ? HDIM : DDIM;               // output row stride (elems)

  __shared__ __align__(16) char smem[131072];

  const int tid = threadIdx.x;
  const int wid = tid >> 6, lane = tid & 63;
  const int wm = wid >> 2, wn = wid & 3;
  const int l15 = lane & 15, l16 = lane >> 4;
  const unsigned khb = (unsigned)kh * 2048u;

  // staging: thread stages rows r0 = tid>>3 and r1 = 64+r0, slot tid&7
  const int r0 = tid >> 3, sl = tid & 7;
  const int r1 = 64 + r0;
  const unsigned d0 = (unsigned)tid * 16u;
  const unsigned d1 = 8192u + (unsigned)tid * 16u;

  unsigned arow[2][2], brow[2][2];
#pragma unroll
  for (int h = 0; h < 2; ++h) {
    const int ga = 128 * h + r0, gb = 128 * h + r1;
    const int ca = (ga < mrem) ? ga : (mrem - 1);
    const int cb = (gb < mrem) ? gb : (mrem - 1);
    if (G1) {
      arow[h][0] = (unsigned)row_token[off0 + m0 + ca] * (unsigned)RSTR + (unsigned)((sl ^ (r0 & 7)) << 4);
      arow[h][1] = (unsigned)row_token[off0 + m0 + cb] * (unsigned)RSTR + (unsigned)((sl ^ (r1 & 7)) << 4);
    } else {
      arow[h][0] = (unsigned)(off0 + m0 + ca) * (unsigned)RSTR + khb + (unsigned)((sl ^ (r0 & 7)) << 4);
      arow[h][1] = (unsigned)(off0 + m0 + cb) * (unsigned)RSTR + khb + (unsigned)((sl ^ (r1 & 7)) << 4);
    }
    brow[h][0] = (unsigned)(n0 + 128 * h + r0) * (unsigned)RSTR + khb + (unsigned)((sl ^ (r0 & 7)) << 4);
    brow[h][1] = (unsigned)(n0 + 128 * h + r1) * (unsigned)RSTR + khb + (unsigned)((sl ^ (r1 & 7)) << 4);
  }

  const char* a_c = (const char*)A;
  const char* b_c = (const char*)(Bw + (size_t)e * (size_t)(HDIM * DDIM));

#define ST_A(dst, h, kt) { gload16(a_c + arow[h][0] + (kt) * 128, smem + (dst) + d0); \
                           gload16(a_c + arow[h][1] + (kt) * 128, smem + (dst) + d1); }
#define ST_B(dst, h, kt) { gload16(b_c + brow[h][0] + (kt) * 128, smem + (dst) + d0); \
                           gload16(b_c + brow[h][1] + (kt) * 128, smem + (dst) + d1); }

  const unsigned aoff0 = (unsigned)(l15 * 128) + (unsigned)((((0 * 4) + l16) ^ (l15 & 7)) << 4);
  const unsigned aoff1 = (unsigned)(l15 * 128) + (unsigned)((((1 * 4) + l16) ^ (l15 & 7)) << 4);

  f32x4 acc[8][4] = {};

  // prologue: A(buf0)<-kt0, B(buf0)<-kt0, B(buf1)<-kt1; drain
  ST_A(0, 0, 0)       ST_A(16384, 1, 0)
  ST_B(32768, 0, 0)   ST_B(49152, 1, 0)
  ST_B(98304, 0, 1)   ST_B(114688, 1, 1)
  asm volatile("s_waitcnt vmcnt(0)" ::: "memory");
  __builtin_amdgcn_s_barrier();

  for (int it = 0; it < 8; ++it) {
    const bool more = (it < 7);
    const int ktA1 = 2 * it + 1, ktN = 2 * it + 2, ktB1 = 2 * it + 3;
#pragma unroll
    for (int H = 0; H < 2; ++H) {
      const char* Ar = smem + H * 65536 + wm * 16384;
      const char* Br = smem + H * 65536 + 32768 + (wn >> 1) * 16384 + (wn & 1) * 8192;
      f16x8 bfr[4][2];
#pragma unroll
      for (int q = 0; q < 4; ++q) {
        if (q == 0) {
#pragma unroll
          for (int n = 0; n < 4; ++n) {
            bfr[n][0] = *(const f16x8*)(Br + n * 2048 + aoff0);
            bfr[n][1] = *(const f16x8*)(Br + n * 2048 + aoff1);
          }
        }
        f16x8 af[2][2];
#pragma unroll
        for (int dm = 0; dm < 2; ++dm) {
          af[dm][0] = *(const f16x8*)(Ar + (2 * q + dm) * 2048 + aoff0);
          af[dm][1] = *(const f16x8*)(Ar + (2 * q + dm) * 2048 + aoff1);
        }
        // one half-tile stage per phase
        if (H == 0) {
          if (q == 0)      { ST_A(65536, 0, ktA1) }
          else if (q == 1) { ST_A(81920, 1, ktA1) }
          else if (q == 2) { if (more) ST_B(32768, 0, ktN) }
          else             { if (more) ST_B(49152, 1, ktN) }
        } else if (more) {
          if (q == 0)      { ST_A(0, 0, ktN) }
          else if (q == 1) { ST_A(16384, 1, ktN) }
          else if (q == 2) { ST_B(98304, 0, ktB1) }
          else             { ST_B(114688, 1, ktB1) }
        }
        __builtin_amdgcn_s_barrier();
        __builtin_amdgcn_s_setprio(1);
#pragma unroll
        for (int dm = 0; dm < 2; ++dm)
#pragma unroll
          for (int n = 0; n < 4; ++n) {
            acc[2 * q + dm][n] = __builtin_amdgcn_mfma_f32_16x16x32_f16(af[dm][0], bfr[n][0], acc[2 * q + dm][n], 0, 0, 0);
            acc[2 * q + dm][n] = __builtin_amdgcn_mfma_f32_16x16x32_f16(af[dm][1], bfr[n][1], acc[2 * q + dm][n], 0, 0, 0);
          }
        __builtin_amdgcn_s_setprio(0);
        if (q == 3) {
          if (H == 0) {
            if (more) { asm volatile("s_waitcnt vmcnt(4)" ::: "memory"); }
            else      { asm volatile("s_waitcnt vmcnt(0)" ::: "memory"); }
            __builtin_amdgcn_sched_barrier(0);
          } else if (more) {
            asm volatile("s_waitcnt vmcnt(4)" ::: "memory");
            __builtin_amdgcn_sched_barrier(0);
          }
        }
        __builtin_amdgcn_s_barrier();
      }
    }
  }
#undef ST_A
#undef ST_B

  // epilogue: (bias+gelu for G1) -> restage 256x256 f16 C in LDS -> coalesced stores
  float bv[4] = {0.f, 0.f, 0.f, 0.f};
  if (G1) {
#pragma unroll
    for (int n = 0; n < 4; ++n)
      bv[n] = bias_g[(size_t)e * HDIM + n0 + wn * 64 + n * 16 + l15];
  }
#pragma unroll
  for (int m = 0; m < 8; ++m) {
#pragma unroll
    for (int j = 0; j < 4; ++j) {
      const int row = wm * 128 + m * 16 + l16 * 4 + j;
#pragma unroll
      for (int n = 0; n < 4; ++n) {
        const int col = wn * 64 + n * 16 + l15;
        float v = acc[m][n][j];
        if (G1) v = gelu_tanh(v + bv[n]);
        *(_Float16*)(smem + row * 512 + ((col * 2) ^ ((row & 15) << 4))) = (_Float16)v;
      }
    }
  }
  __syncthreads();
  {
    const int row = tid >> 1, half = tid & 1;
    if (row < mrem) {
      _Float16* outp = (G1 ? outb : (outb + (size_t)kh * NPAIR * DDIM))
                       + (size_t)(off0 + m0 + row) * OSTR + n0 + half * 128;
#pragma unroll
      for (int i = 0; i < 16; ++i) {
        f16x8 v = *(const f16x8*)(smem + row * 512 + ((half * 256 + i * 16) ^ ((row & 15) << 4)));
        *(f16x8*)(outp + i * 8) = v;
      }
    }
  }
}

// ---------------- combine: out[t] = sum_k tw[t,k] * (sum_p y_p[g_k] + b2[e_k]) ----------------
__global__ __launch_bounds__(256) void k_combine(const _Float16* __restrict__ yb,
    const int* __restrict__ inv, const int* __restrict__ tidx,
    const float* __restrict__ tw, const float* __restrict__ b2,
    float* __restrict__ out) {
  const int t  = blockIdx.x * 2 + (threadIdx.x >> 7);
  const int c8 = (threadIdx.x & 127) * 8;
  const int g0 = inv[2 * t],  g1 = inv[2 * t + 1];
  const int e0 = tidx[2 * t], e1 = tidx[2 * t + 1];
  const float w0 = tw[2 * t], w1 = tw[2 * t + 1];
  float s0[8] = {0,0,0,0,0,0,0,0}, s1[8] = {0,0,0,0,0,0,0,0};
#pragma unroll
  for (int p = 0; p < NSPLIT; ++p) {
    const _Float16* yp = yb + (size_t)p * NPAIR * DDIM;
    f16x8 a = *(const f16x8*)(yp + (size_t)g0 * DDIM + c8);
    f16x8 b = *(const f16x8*)(yp + (size_t)g1 * DDIM + c8);
#pragma unroll
    for (int i = 0; i < 8; ++i) { s0[i] += (float)a[i]; s1[i] += (float)b[i]; }
  }
  float o[8];
#pragma unroll
  for (int i = 0; i < 8; ++i) {
    float bA = b2[(size_t)e0 * DDIM + c8 + i];
    float bB = b2[(size_t)e1 * DDIM + c8 + i];
    o[i] = w0 * (s0[i] + bA) + w1 * (s1[i] + bB);
  }
  float* op = out + (size_t)t * DDIM + c8;
  *(float4*)op       = make_float4(o[0], o[1], o[2], o[3]);
  *(float4*)(op + 4) = make_float4(o[4], o[5], o[6], o[7]);
}

// ---------------- host ----------------
// layout: small meta | xb 8MB | wtA (w1t, later yb 4x16MB) 64MB | wtB (w2t) 64MB | hb 64MB
extern "C" void kernel_launch(void* const* d_in, const int* in_sizes, int n_in,
                              void* d_out, int out_size, void* d_ws, size_t ws_size,
                              hipStream_t stream) {
  const float* x  = (const float*)d_in[0];
  const float* rw = (const float*)d_in[1];
  const float* rb = (const float*)d_in[2];
  const float* w1 = (const float*)d_in[3];
  const float* b1 = (const float*)d_in[4];
  const float* w2 = (const float*)d_in[5];
  const float* b2 = (const float*)d_in[6];
  float* out = (float*)d_out;
  char* ws = (char*)d_ws;

  int*      tidx    = (int*)(ws + 0);               // 32KB
  float*    tw      = (float*)(ws + 32768);         // 32KB
  int*      tcount  = (int*)(ws + 65536);
  int*      tlist   = (int*)(ws + 65544);           // ~160B
  int*      offs    = (int*)(ws + 65856);           // 36B
  int*      row_tok = (int*)(ws + 66048);           // 32KB
  float*    row_w   = (float*)(ws + 98816);         // 32KB
  int*      inv     = (int*)(ws + 131584);          // 32KB
  _Float16* xb      = (_Float16*)(ws + 164352);     // 8MB
  _Float16* wtA     = (_Float16*)(ws + 8552960);    // 64MB: w1t, dead after gemm1
  _Float16* wtB     = (_Float16*)(ws + 75661824);   // 64MB: w2t
  _Float16* hb      = (_Float16*)(ws + 142770688);  // 64MB
  _Float16* yb      = wtA;                          // 4x16MB partials reuse w1t space

  k_router<<<dim3(TOK / 4), 256, 0, stream>>>(x, rw, rb, tidx, tw, xb);
  k_scan<<<dim3(1), 1024, 0, stream>>>(tidx, tw, offs, row_tok, row_w, inv, tlist, tcount);
  k_transpose2<<<dim3(1024, 2 * NEXP), 256, 0, stream>>>(w1, w2, wtA, wtB);
  k_gemm256<true><<<dim3(MAXT * 16), 512, 0, stream>>>(
      xb, wtA, b1, offs, row_tok, tlist, tcount, hb);
  k_gemm256<false><<<dim3(MAXT * 16), 512, 0, stream>>>(
      hb, wtB, b2, offs, row_tok, tlist, tcount, yb);
  k_combine<<<dim3(TOK / 2), 256, 0, stream>>>(yb, inv, tidx, tw, b2, out);
}

// Round 15
// 346.079 us; speedup vs baseline: 1.0324x; 1.0324x over previous
//
#include <hip/hip_runtime.h>
#include <hip/hip_bf16.h>

#define TOK   4096            // B*S
#define DDIM  1024
#define NEXP  8
#define HDIM  4096
#define KSEL  2
#define NPAIR (TOK * KSEL)    // 8192
#define NSPLIT 2              // gemm2 split-K factor
#define MAXT  72              // max populated (expert, 128-row M-tile) entries

typedef __attribute__((ext_vector_type(8))) _Float16 f16x8;
typedef __attribute__((ext_vector_type(4))) _Float16 f16x4;
typedef __attribute__((ext_vector_type(4))) float    f32x4;

__device__ __forceinline__ void gload16(const void* g, void* l) {
  __builtin_amdgcn_global_load_lds((const __attribute__((address_space(1))) void*)g,
                                   (__attribute__((address_space(3))) void*)l, 16, 0, 0);
}

__device__ __forceinline__ float gelu_tanh(float u) {
  float inner = 0.7978845608028654f * (u + 0.044715f * u * u * u);
  float t2 = __expf(2.f * inner);
  return u - u / (t2 + 1.f);     // == 0.5*u*(1+tanh(inner)), overflow-safe
}

// ---------------- prep: router (blocks 0..1023) + both weight transposes ----------------
// Router path: one wave per token, fused x->fp16. Transpose path: 64x64 tiles,
// fp32 -> fp16 transposed, 16B out-stores. Merged so the ~10us router rides
// under the memory-bound transpose wave (single launch, no stream gap).
__global__ __launch_bounds__(256) void k_prep(const float* __restrict__ x,
    const float* __restrict__ rw, const float* __restrict__ rb,
    const float* __restrict__ w1, const float* __restrict__ w2,
    int* __restrict__ tidx, float* __restrict__ tw, _Float16* __restrict__ xb,
    _Float16* __restrict__ w1t, _Float16* __restrict__ w2t) {
  if (blockIdx.x < 1024) {
    // ---- router ----
    const int t    = blockIdx.x * 4 + (threadIdx.x >> 6);
    const int lane = threadIdx.x & 63;
    const float* xr = x + (size_t)t * DDIM;
    _Float16*   xbr = xb + (size_t)t * DDIM;
    float acc[NEXP];
#pragma unroll
    for (int e = 0; e < NEXP; ++e) acc[e] = 0.f;
    for (int d0 = lane * 4; d0 < DDIM; d0 += 256) {
      const float4 xv = *(const float4*)(xr + d0);
      f16x4 hx;
      hx[0] = (_Float16)xv.x; hx[1] = (_Float16)xv.y;
      hx[2] = (_Float16)xv.z; hx[3] = (_Float16)xv.w;
      *(f16x4*)(xbr + d0) = hx;
#pragma unroll
      for (int i = 0; i < 4; ++i) {
        const float xs = (&xv.x)[i];
        const float4 r0 = *(const float4*)(rw + (size_t)(d0 + i) * NEXP);
        const float4 r1 = *(const float4*)(rw + (size_t)(d0 + i) * NEXP + 4);
        acc[0] += xs * r0.x; acc[1] += xs * r0.y; acc[2] += xs * r0.z; acc[3] += xs * r0.w;
        acc[4] += xs * r1.x; acc[5] += xs * r1.y; acc[6] += xs * r1.z; acc[7] += xs * r1.w;
      }
    }
#pragma unroll
    for (int e = 0; e < NEXP; ++e) {
      float v = acc[e];
#pragma unroll
      for (int s = 32; s; s >>= 1) v += __shfl_xor(v, s, 64);
      acc[e] = v;
    }
    if (lane == 0) {
      float lg[NEXP];
#pragma unroll
      for (int e = 0; e < NEXP; ++e) lg[e] = acc[e] + rb[e];
      int i0 = 0;
#pragma unroll
      for (int e = 1; e < NEXP; ++e) if (lg[e] > lg[i0]) i0 = e;
      int i1 = -1; float best = -3.4e38f;
#pragma unroll
      for (int e = 0; e < NEXP; ++e) {
        if (e == i0) continue;
        if (lg[e] > best) { best = lg[e]; i1 = e; }
      }
      float w0 = 1.f / (1.f + expf(lg[i1] - lg[i0]));
      tidx[t * 2]     = i0;  tidx[t * 2 + 1] = i1;
      tw[t * 2]       = w0;  tw[t * 2 + 1]   = 1.f - w0;
    }
    return;
  }
  // ---- transpose ----
  __shared__ _Float16 tile[64][66];
  const int bx = blockIdx.x - 1024;
  const int zz = bx >> 10;              // 0..15
  const int xx = bx & 1023;
  const float* ip; _Float16* op; int Rr, Cc, i0, j0;
  if (zz < NEXP) {
    ip = w1 + (size_t)zz * DDIM * HDIM;  op = w1t + (size_t)zz * DDIM * HDIM;
    Rr = DDIM; Cc = HDIM;
    i0 = (xx >> 6) * 64; j0 = (xx & 63) * 64;
  } else {
    ip = w2 + (size_t)(zz - NEXP) * HDIM * DDIM;  op = w2t + (size_t)(zz - NEXP) * HDIM * DDIM;
    Rr = HDIM; Cc = DDIM;
    i0 = (xx >> 4) * 64; j0 = (xx & 15) * 64;
  }
  const int tx = threadIdx.x & 15, ty = threadIdx.x >> 4;
#pragma unroll
  for (int rr = 0; rr < 4; ++rr) {
    int r = ty + rr * 16;
    float4 v = *(const float4*)(ip + (size_t)(i0 + r) * Cc + j0 + tx * 4);
    tile[r][tx * 4 + 0] = (_Float16)v.x;
    tile[r][tx * 4 + 1] = (_Float16)v.y;
    tile[r][tx * 4 + 2] = (_Float16)v.z;
    tile[r][tx * 4 + 3] = (_Float16)v.w;
  }
  __syncthreads();
  {
    const int c  = threadIdx.x >> 2;         // 64 out-rows (= in cols)
    const int s0 = (threadIdx.x & 3) * 16;   // 16 elems per thread
    f16x8 v0, v1;
#pragma unroll
    for (int k = 0; k < 8; ++k) { v0[k] = tile[s0 + k][c]; v1[k] = tile[s0 + 8 + k][c]; }
    _Float16* outp = op + (size_t)(j0 + c) * Rr + i0 + s0;
    *(f16x8*)outp       = v0;
    *(f16x8*)(outp + 8) = v1;
  }
}

// ---------------- scan: histogram + prefix + scatter + compact 128-row tile list ----------------
__global__ __launch_bounds__(1024) void k_scan(const int* __restrict__ tidx,
                       const float* __restrict__ tw,
                       int* __restrict__ offs,
                       int* __restrict__ row_token, float* __restrict__ row_w,
                       int* __restrict__ inv,
                       int* __restrict__ tlist, int* __restrict__ tcount) {
  __shared__ int hist[NEXP];
  __shared__ int soff[NEXP + 1];
  __shared__ int scur[NEXP];
  if (threadIdx.x < NEXP) hist[threadIdx.x] = 0;
  __syncthreads();
  const int lane = threadIdx.x & 63;
  int e_loc[NPAIR / 1024];
#pragma unroll
  for (int it = 0; it < NPAIR / 1024; ++it) {
    const int p = it * 1024 + threadIdx.x;
    const int e = tidx[p];
    e_loc[it] = e;
#pragma unroll
    for (int ee = 0; ee < NEXP; ++ee) {
      unsigned long long m = __ballot(e == ee);
      if (m && lane == 0) atomicAdd(&hist[ee], __popcll(m));
    }
  }
  __syncthreads();
  if (threadIdx.x == 0) {
    int run = 0;
    for (int e = 0; e < NEXP; ++e) { soff[e] = run; scur[e] = run; run += hist[e]; }
    soff[NEXP] = run;
    for (int e = 0; e <= NEXP; ++e) offs[e] = soff[e];
    int cnt = 0;
    for (int e = 0; e < NEXP; ++e) {
      const int ne = soff[e + 1] - soff[e];
      for (int m = 0; m < ne; m += 128) tlist[cnt++] = (e << 8) | (m >> 7);
    }
    *tcount = cnt;
  }
  __syncthreads();
#pragma unroll
  for (int it = 0; it < NPAIR / 1024; ++it) {
    const int p = it * 1024 + threadIdx.x;
    const int e = e_loc[it];
    int pos = 0;
#pragma unroll
    for (int ee = 0; ee < NEXP; ++ee) {
      unsigned long long m = __ballot(e == ee);
      if (!m) continue;
      int base = 0;
      if (lane == 0) base = atomicAdd(&scur[ee], __popcll(m));
      base = __shfl(base, 0, 64);
      if (e == ee) pos = base + __popcll(m & ((1ull << lane) - 1ull));
    }
    row_token[pos] = p >> 1;
    row_w[pos]     = tw[p];
    inv[p]         = pos;
  }
}

#define BM 128
#define BN 128
#define BKK 32

// r7-proven GEMM body on the compact tile list (r13, best measured config).

// ---------------- GEMM1: h = gelu(X_gathered @ w1t^T + b1), fp16 out ----------------
__global__ __launch_bounds__(256) void k_gemm1(
    const _Float16* __restrict__ xb,    // [TOK][DDIM]
    const _Float16* __restrict__ w1t,   // [NEXP][HDIM][DDIM]
    const float* __restrict__ b1,       // [NEXP][HDIM]
    const int* __restrict__ offs,
    const int* __restrict__ row_token,
    const int* __restrict__ tlist, const int* __restrict__ tcount,
    _Float16* __restrict__ hbuf) {      // [NPAIR][HDIM]
  const int bid = blockIdx.x;
  const int t   = bid >> 5;             // 32 n-tiles per work item
  if (t >= *tcount) return;
  const int tl  = tlist[t];
  const int e   = tl >> 8;
  const int m0  = (tl & 255) * BM;
  const int n0  = (bid & 31) * BN;
  const int off0 = offs[e];
  const int ne   = offs[e + 1] - off0;
  const int mrem = ne - m0;

  __shared__ __align__(16) char smem[32768];

  const int tid = threadIdx.x;
  const int wv = tid >> 6, lane = tid & 63;
  const int l15 = lane & 15;
  const int wr = wv >> 1, wc = wv & 1;

  const int rA0 = (wv * 2 + 0) * 16 + (lane >> 2);
  const int rA1 = (wv * 2 + 1) * 16 + (lane >> 2);
  const char* a_c = (const char*)xb;
  const char* b_c = (const char*)(w1t + (size_t)e * HDIM * DDIM);
  const int rc0 = (rA0 < mrem) ? rA0 : (mrem - 1);
  const int rc1 = (rA1 < mrem) ? rA1 : (mrem - 1);
  const char* ap0 = a_c + (size_t)row_token[off0 + m0 + rc0] * (DDIM * 2)
                        + (((lane & 3) ^ ((rA0 >> 1) & 3)) << 4);
  const char* ap1 = a_c + (size_t)row_token[off0 + m0 + rc1] * (DDIM * 2)
                        + (((lane & 3) ^ ((rA1 >> 1) & 3)) << 4);
  const char* bp0 = b_c + (size_t)(n0 + rA0) * (DDIM * 2)
                        + (((lane & 3) ^ ((rA0 >> 1) & 3)) << 4);
  const char* bp1 = b_c + (size_t)(n0 + rA1) * (DDIM * 2)
                        + (((lane & 3) ^ ((rA1 >> 1) & 3)) << 4);
  char* ldsA0 = smem + (wv * 2 + 0) * 1024;
  char* ldsA1 = smem + (wv * 2 + 1) * 1024;
  char* ldsB0 = smem + 16384 + (wv * 2 + 0) * 1024;
  char* ldsB1 = smem + 16384 + (wv * 2 + 1) * 1024;

  const unsigned foff = (unsigned)(((lane >> 4) ^ ((l15 >> 1) & 3)) << 4);

  f32x4 acc[4][4] = {};
  const int NT = DDIM / BKK;   // 32

  gload16(ap0, ldsA0); gload16(ap1, ldsA1);
  gload16(bp0, ldsB0); gload16(bp1, ldsB1);

#pragma unroll 2
  for (int ks = 0; ks < NT; ++ks) {
    const int cur = ks & 1;
    if (ks + 1 < NT) {
      const int nb = (cur ^ 1) * 8192;
      const size_t kb = (size_t)(ks + 1) * 64;
      gload16(ap0 + kb, ldsA0 + nb); gload16(ap1 + kb, ldsA1 + nb);
      gload16(bp0 + kb, ldsB0 + nb); gload16(bp1 + kb, ldsB1 + nb);
      asm volatile("s_waitcnt vmcnt(4)" ::: "memory");
    } else {
      asm volatile("s_waitcnt vmcnt(0)" ::: "memory");
    }
    __builtin_amdgcn_sched_barrier(0);
    __builtin_amdgcn_s_barrier();
    const char* Ab = smem + cur * 8192;
    const char* Bb = smem + 16384 + cur * 8192;
    f16x8 af[4], bfr[4];
#pragma unroll
    for (int m = 0; m < 4; ++m)
      af[m] = *(const f16x8*)(Ab + (wr * 64 + m * 16 + l15) * 64 + foff);
#pragma unroll
    for (int n = 0; n < 4; ++n)
      bfr[n] = *(const f16x8*)(Bb + (wc * 64 + n * 16 + l15) * 64 + foff);
#pragma unroll
    for (int m = 0; m < 4; ++m)
#pragma unroll
      for (int n = 0; n < 4; ++n)
        acc[m][n] = __builtin_amdgcn_mfma_f32_16x16x32_f16(af[m], bfr[n], acc[m][n], 0, 0, 0);
    __builtin_amdgcn_sched_barrier(0);
    __builtin_amdgcn_s_barrier();
  }

  float bias[4];
#pragma unroll
  for (int n = 0; n < 4; ++n)
    bias[n] = b1[(size_t)e * HDIM + n0 + wc * 64 + n * 16 + l15];
#pragma unroll
  for (int m = 0; m < 4; ++m) {
#pragma unroll
    for (int j = 0; j < 4; ++j) {
      int row = wr * 64 + m * 16 + (lane >> 4) * 4 + j;
#pragma unroll
      for (int n = 0; n < 4; ++n) {
        int col = wc * 64 + n * 16 + l15;
        *(_Float16*)(smem + (row << 8) + (((col << 1) ^ ((row & 15) << 4)))) =
            (_Float16)gelu_tanh(acc[m][n][j] + bias[n]);
      }
    }
  }
  __syncthreads();
  {
    const int srow = tid >> 1, half = tid & 1;
    if (srow < mrem) {
      _Float16* hr = hbuf + (size_t)(off0 + m0 + srow) * HDIM + n0 + half * 64;
#pragma unroll
      for (int i = 0; i < 8; ++i) {
        f16x8 v = *(const f16x8*)(smem + (srow << 8) + (((half * 128 + i * 16) ^ ((srow & 15) << 4))));
        *(f16x8*)(hr + i * 8) = v;
      }
    }
  }
}

// ---------------- GEMM2 (split-K=2): ypart[kh] = H @ w2t^T ----------------
__global__ __launch_bounds__(256) void k_gemm2(
    const _Float16* __restrict__ hbuf,  // [NPAIR][HDIM]
    const _Float16* __restrict__ w2t,   // [NEXP][DDIM][HDIM]
    const int* __restrict__ offs,
    const int* __restrict__ tlist, const int* __restrict__ tcount,
    _Float16* __restrict__ yb) {        // [NSPLIT][NPAIR][DDIM] partials
  const int bid = blockIdx.x;
  const int t   = bid >> 4;             // 8 nx * 2 kh per work item
  if (t >= *tcount) return;
  const int tl  = tlist[t];
  const int e   = tl >> 8;
  const int m0  = (tl & 255) * BM;
  const int sub = bid & 15;
  const int kh  = sub >> 3;
  const int n0  = (sub & 7) * BN;
  const int off0 = offs[e];
  const int ne   = offs[e + 1] - off0;
  const int mrem = ne - m0;

  __shared__ __align__(16) char smem[32768];

  const int tid = threadIdx.x;
  const int wv = tid >> 6, lane = tid & 63;
  const int l15 = lane & 15;
  const int wr = wv >> 1, wc = wv & 1;

  const int rA0 = (wv * 2 + 0) * 16 + (lane >> 2);
  const int rA1 = (wv * 2 + 1) * 16 + (lane >> 2);
  const char* a_c = (const char*)hbuf;
  const char* b_c = (const char*)(w2t + (size_t)e * DDIM * HDIM);
  const int rc0 = (rA0 < mrem) ? rA0 : (mrem - 1);
  const int rc1 = (rA1 < mrem) ? rA1 : (mrem - 1);
  const size_t khb = (size_t)kh * ((HDIM / NSPLIT) * 2);
  const char* ap0 = a_c + (size_t)(off0 + m0 + rc0) * (HDIM * 2) + khb
                        + (((lane & 3) ^ ((rA0 >> 1) & 3)) << 4);
  const char* ap1 = a_c + (size_t)(off0 + m0 + rc1) * (HDIM * 2) + khb
                        + (((lane & 3) ^ ((rA1 >> 1) & 3)) << 4);
  const char* bp0 = b_c + (size_t)(n0 + rA0) * (HDIM * 2) + khb
                        + (((lane & 3) ^ ((rA0 >> 1) & 3)) << 4);
  const char* bp1 = b_c + (size_t)(n0 + rA1) * (HDIM * 2) + khb
                        + (((lane & 3) ^ ((rA1 >> 1) & 3)) << 4);
  char* ldsA0 = smem + (wv * 2 + 0) * 1024;
  char* ldsA1 = smem + (wv * 2 + 1) * 1024;
  char* ldsB0 = smem + 16384 + (wv * 2 + 0) * 1024;
  char* ldsB1 = smem + 16384 + (wv * 2 + 1) * 1024;

  const unsigned foff = (unsigned)(((lane >> 4) ^ ((l15 >> 1) & 3)) << 4);

  f32x4 acc[4][4] = {};
  const int NT = (HDIM / NSPLIT) / BKK;   // 64

  gload16(ap0, ldsA0); gload16(ap1, ldsA1);
  gload16(bp0, ldsB0); gload16(bp1, ldsB1);

#pragma unroll 2
  for (int ks = 0; ks < NT; ++ks) {
    const int cur = ks & 1;
    if (ks + 1 < NT) {
      const int nb = (cur ^ 1) * 8192;
      const size_t kb = (size_t)(ks + 1) * 64;
      gload16(ap0 + kb, ldsA0 + nb); gload16(ap1 + kb, ldsA1 + nb);
      gload16(bp0 + kb, ldsB0 + nb); gload16(bp1 + kb, ldsB1 + nb);
      asm volatile("s_waitcnt vmcnt(4)" ::: "memory");
    } else {
      asm volatile("s_waitcnt vmcnt(0)" ::: "memory");
    }
    __builtin_amdgcn_sched_barrier(0);
    __builtin_amdgcn_s_barrier();
    const char* Ab = smem + cur * 8192;
    const char* Bb = smem + 16384 + cur * 8192;
    f16x8 af[4], bfr[4];
#pragma unroll
    for (int m = 0; m < 4; ++m)
      af[m] = *(const f16x8*)(Ab + (wr * 64 + m * 16 + l15) * 64 + foff);
#pragma unroll
    for (int n = 0; n < 4; ++n)
      bfr[n] = *(const f16x8*)(Bb + (wc * 64 + n * 16 + l15) * 64 + foff);
#pragma unroll
    for (int m = 0; m < 4; ++m)
#pragma unroll
      for (int n = 0; n < 4; ++n)
        acc[m][n] = __builtin_amdgcn_mfma_f32_16x16x32_f16(af[m], bfr[n], acc[m][n], 0, 0, 0);
    __builtin_amdgcn_sched_barrier(0);
    __builtin_amdgcn_s_barrier();
  }

  _Float16* ypart = yb + (size_t)kh * NPAIR * DDIM;
#pragma unroll
  for (int m = 0; m < 4; ++m) {
#pragma unroll
    for (int j = 0; j < 4; ++j) {
      int row = wr * 64 + m * 16 + (lane >> 4) * 4 + j;
#pragma unroll
      for (int n = 0; n < 4; ++n) {
        int col = wc * 64 + n * 16 + l15;
        *(_Float16*)(smem + (row << 8) + (((col << 1) ^ ((row & 15) << 4)))) =
            (_Float16)acc[m][n][j];
      }
    }
  }
  __syncthreads();
  {
    const int srow = tid >> 1, half = tid & 1;
    if (srow < mrem) {
      _Float16* yr = ypart + (size_t)(off0 + m0 + srow) * DDIM + n0 + half * 64;
#pragma unroll
      for (int i = 0; i < 8; ++i) {
        f16x8 v = *(const f16x8*)(smem + (srow << 8) + (((half * 128 + i * 16) ^ ((srow & 15) << 4))));
        *(f16x8*)(yr + i * 8) = v;
      }
    }
  }
}

// ---------------- combine: out[t] = sum_k tw[t,k] * (y0[g]+y1[g] + b2[e_k]) ----------------
__global__ __launch_bounds__(256) void k_combine(const _Float16* __restrict__ yb,
    const int* __restrict__ inv, const int* __restrict__ tidx,
    const float* __restrict__ tw, const float* __restrict__ b2,
    float* __restrict__ out) {
  const int t  = blockIdx.x * 2 + (threadIdx.x >> 7);
  const int c8 = (threadIdx.x & 127) * 8;
  const int g0 = inv[2 * t],  g1 = inv[2 * t + 1];
  const int e0 = tidx[2 * t], e1 = tidx[2 * t + 1];
  const float w0 = tw[2 * t], w1 = tw[2 * t + 1];
  const _Float16* y1p = yb + (size_t)NPAIR * DDIM;
  f16x8 a0 = *(const f16x8*)(yb  + (size_t)g0 * DDIM + c8);
  f16x8 a1 = *(const f16x8*)(y1p + (size_t)g0 * DDIM + c8);
  f16x8 b0 = *(const f16x8*)(yb  + (size_t)g1 * DDIM + c8);
  f16x8 b1v = *(const f16x8*)(y1p + (size_t)g1 * DDIM + c8);
  float o[8];
#pragma unroll
  for (int i = 0; i < 8; ++i) {
    float bA = b2[(size_t)e0 * DDIM + c8 + i];
    float bB = b2[(size_t)e1 * DDIM + c8 + i];
    o[i] = w0 * ((float)a0[i] + (float)a1[i] + bA) + w1 * ((float)b0[i] + (float)b1v[i] + bB);
  }
  float* op = out + (size_t)t * DDIM + c8;
  *(float4*)op       = make_float4(o[0], o[1], o[2], o[3]);
  *(float4*)(op + 4) = make_float4(o[4], o[5], o[6], o[7]);
}

// ---------------- host ----------------
// layout: small meta | xb 8MB | wtA (w1t, later yb 2x16MB) 64MB | wtB (w2t) 64MB | hb 64MB
extern "C" void kernel_launch(void* const* d_in, const int* in_sizes, int n_in,
                              void* d_out, int out_size, void* d_ws, size_t ws_size,
                              hipStream_t stream) {
  const float* x  = (const float*)d_in[0];
  const float* rw = (const float*)d_in[1];
  const float* rb = (const float*)d_in[2];
  const float* w1 = (const float*)d_in[3];
  const float* b1 = (const float*)d_in[4];
  const float* w2 = (const float*)d_in[5];
  const float* b2 = (const float*)d_in[6];
  float* out = (float*)d_out;
  char* ws = (char*)d_ws;

  int*      tidx    = (int*)(ws + 0);               // 32KB
  float*    tw      = (float*)(ws + 32768);         // 32KB
  int*      tcount  = (int*)(ws + 65536);
  int*      tlist   = (int*)(ws + 65544);           // 288B
  int*      offs    = (int*)(ws + 65856);           // 36B
  int*      row_tok = (int*)(ws + 66048);           // 32KB
  float*    row_w   = (float*)(ws + 98816);         // 32KB
  int*      inv     = (int*)(ws + 131584);          // 32KB
  _Float16* xb      = (_Float16*)(ws + 164352);     // 8MB
  _Float16* wtA     = (_Float16*)(ws + 8552960);    // 64MB: w1t, dead after gemm1
  _Float16* wtB     = (_Float16*)(ws + 75661824);   // 64MB: w2t
  _Float16* hb      = (_Float16*)(ws + 142770688);  // 64MB
  _Float16* yb      = wtA;                          // 2x16MB partials reuse w1t space

  k_prep<<<dim3(1024 + 16 * 1024), 256, 0, stream>>>(x, rw, rb, w1, w2,
                                                     tidx, tw, xb, wtA, wtB);
  k_scan<<<dim3(1), 1024, 0, stream>>>(tidx, tw, offs, row_tok, row_w, inv, tlist, tcount);
  k_gemm1<<<dim3(MAXT * 32), 256, 0, stream>>>(xb, wtA, b1, offs, row_tok, tlist, tcount, hb);
  k_gemm2<<<dim3(MAXT * 16), 256, 0, stream>>>(hb, wtB, offs, tlist, tcount, yb);
  k_combine<<<dim3(TOK / 2), 256, 0, stream>>>(yb, inv, tidx, tw, b2, out);
}